// Round 6
// baseline (1154.541 us; speedup 1.0000x reference)
//
#include <hip/hip_runtime.h>

// Mesh2: out3 = [out1||out2] @ W_comb^T + b_comb ; out4 = mean(self+3nbrs) @ W_agg^T + b_agg
// R2: fused, 600us, latency-bound. R3/R4: reg-stage pipeline spilled (VGPR cap 128 immovable,
//     +860MB scratch HBM traffic) -> 1100us.
// R5: LINEARITY SPLIT: Y = out2@W_agg^T (dense GEMM, bf16 in ws), then
//     out4 = 0.25*(Y[n]+Y[i0]+Y[i1]+Y[i2]) + b (gather AFTER GEMM, in output space).
// R6: compile fix — __builtin_nontemporal_store needs clang ext-vector, not HIP float4.

typedef __bf16 bf16x8 __attribute__((ext_vector_type(8)));
typedef float f32x4 __attribute__((ext_vector_type(4)));

#define N_NODES 200000
#define BM 32
#define NTILES (N_NODES / BM)  // 6250
#define ROWC 520               // 512 + 8 pad (bf16)
#define ROWA 264               // fallback only
#define GRID_A 512
#define GRID_B 2048

__device__ __forceinline__ unsigned short f2bf(float x) {
  union { float f; unsigned int u; } v; v.f = x;
  return (unsigned short)((v.u + 0x7FFFu + ((v.u >> 16) & 1u)) >> 16);  // RNE
}

__device__ __forceinline__ void st_bf4(unsigned short* p, float4 f) {
  uint2 w;
  w.x = (unsigned int)f2bf(f.x) | ((unsigned int)f2bf(f.y) << 16);
  w.y = (unsigned int)f2bf(f.z) | ((unsigned int)f2bf(f.w) << 16);
  *reinterpret_cast<uint2*>(p) = w;
}

// Pack W (f32, row-major [O][K]) -> bf16 MFMA-B-fragment-linear layout:
// tile (nt,kt): lane l holds W[nt*16 + (l&15)][kt*32 + (l>>4)*8 + j] at P[tile*512 + l*8 + j].
__global__ void pack_w_kernel(const float* __restrict__ Wc,
                              const float* __restrict__ Wa,
                              unsigned short* __restrict__ Pc,
                              unsigned short* __restrict__ Pa) {
  int t = blockIdx.x * 256 + threadIdx.x;
  if (t >= (512 + 256) * 64) return;
  int lane = t & 63;
  int tile = t >> 6;
  const float* W;
  unsigned short* P;
  int K, kt_n;
  if (tile < 512) { W = Wc; P = Pc; K = 512; kt_n = 16; }
  else { tile -= 512; W = Wa; P = Pa; K = 256; kt_n = 8; }
  int nt = tile / kt_n;
  int kt = tile - nt * kt_n;
  int row = nt * 16 + (lane & 15);
  int k0 = kt * 32 + (lane >> 4) * 8;
  const float* src = W + (size_t)row * K + k0;
  unsigned short* dst = P + (size_t)tile * 512 + lane * 8;
#pragma unroll
  for (int j = 0; j < 8; ++j) dst[j] = f2bf(src[j]);
}

// ---------------- Kernel A: dense GEMM (out3 f32 + Y bf16), 2-deep pipeline ----------------
__global__ __launch_bounds__(512, 4) void gemm_kernel(
    const float* __restrict__ out1, const float* __restrict__ out2,
    const unsigned short* __restrict__ Pc, const unsigned short* __restrict__ Pa,
    const float* __restrict__ b_comb,
    float* __restrict__ out3, unsigned short* __restrict__ Y) {
  __shared__ unsigned short Acomb[BM * ROWC];

  const int tid = threadIdx.x;
  const int ln = tid >> 4, c16 = tid & 15;       // stage role: node, chunk
  const int wave = tid >> 6, lane = tid & 63;
  const int l15 = lane & 15, l4 = lane >> 4;

  float bcv[4];
#pragma unroll
  for (int n = 0; n < 4; ++n) bcv[n] = b_comb[wave * 64 + n * 16 + l15];

  float4 s1[4], s2[4];  // 32 VGPRs staged — fits under the 128 cap
  auto issue = [&](int t) {
    const size_t gn = (size_t)t * BM + ln;
    const float4* r1 = reinterpret_cast<const float4*>(out1 + gn * 256);
    const float4* r2 = reinterpret_cast<const float4*>(out2 + gn * 256);
#pragma unroll
    for (int r = 0; r < 4; ++r) {
      s1[r] = r1[c16 + 16 * r];
      s2[r] = r2[c16 + 16 * r];
    }
  };

  int t = blockIdx.x;
  issue(t);  // GRID_A=512 < NTILES always
  while (t < NTILES) {
    // barrier 1: all waves done reading LDS of previous tile (reads complete before
    // their consuming MFMAs issued, which precede this barrier)
    __builtin_amdgcn_s_barrier();

#pragma unroll
    for (int r = 0; r < 4; ++r) {
      const int cc = c16 + 16 * r;
      st_bf4(&Acomb[ln * ROWC + cc * 4], s1[r]);        // cols 0..255   = out1
      st_bf4(&Acomb[ln * ROWC + 256 + cc * 4], s2[r]);  // cols 256..511 = out2
    }

    // prefetch next tile NOW; raw barrier below does not drain vmcnt
    const int tn = t + GRID_A;
    if (tn < NTILES) issue(tn);

    asm volatile("s_waitcnt lgkmcnt(0)" ::: "memory");  // my ds_writes visible
    __builtin_amdgcn_s_barrier();                       // barrier 2: tile ready

    const int nt0 = wave * 4;
    const long long node0 = (long long)t * BM;

    // ---- out3 = [o1|o2] @ Wc^T + b (K=512), acc scope tight: 32 VGPRs ----
    {
      f32x4 acc[2][4];
#pragma unroll
      for (int m = 0; m < 2; ++m)
#pragma unroll
        for (int n = 0; n < 4; ++n) acc[m][n] = (f32x4){0.f, 0.f, 0.f, 0.f};

      const unsigned short* pc = Pc + (size_t)nt0 * 16 * 512 + lane * 8;
      const unsigned short* ab = &Acomb[(size_t)l15 * ROWC + l4 * 8];
#pragma unroll
      for (int kt = 0; kt < 16; ++kt) {
        bf16x8 a0 = *reinterpret_cast<const bf16x8*>(ab + kt * 32);
        bf16x8 a1 = *reinterpret_cast<const bf16x8*>(ab + 16 * ROWC + kt * 32);
#pragma unroll
        for (int n = 0; n < 4; ++n) {
          bf16x8 b = *reinterpret_cast<const bf16x8*>(pc + ((size_t)n * 16 + kt) * 512);
          acc[0][n] = __builtin_amdgcn_mfma_f32_16x16x32_bf16(a0, b, acc[0][n], 0, 0, 0);
          acc[1][n] = __builtin_amdgcn_mfma_f32_16x16x32_bf16(a1, b, acc[1][n], 0, 0, 0);
        }
      }
      float* o3 = out3 + node0 * 512 + wave * 64 + l15;
#pragma unroll
      for (int m = 0; m < 2; ++m)
#pragma unroll
        for (int r = 0; r < 4; ++r) {
          float* p = o3 + (long long)(m * 16 + l4 * 4 + r) * 512;
#pragma unroll
          for (int n = 0; n < 4; ++n)
            __builtin_nontemporal_store(acc[m][n][r] + bcv[n], p + n * 16);
        }
    }

    // ---- Y = o2 @ Wa^T (K=256, A = Acomb cols 256..511), bf16 out, cached ----
    {
      f32x4 acc[2][4];
#pragma unroll
      for (int m = 0; m < 2; ++m)
#pragma unroll
        for (int n = 0; n < 4; ++n) acc[m][n] = (f32x4){0.f, 0.f, 0.f, 0.f};

      const unsigned short* pa = Pa + (size_t)nt0 * 8 * 512 + lane * 8;
      const unsigned short* ab = &Acomb[(size_t)l15 * ROWC + 256 + l4 * 8];
#pragma unroll
      for (int kt = 0; kt < 8; ++kt) {
        bf16x8 a0 = *reinterpret_cast<const bf16x8*>(ab + kt * 32);
        bf16x8 a1 = *reinterpret_cast<const bf16x8*>(ab + 16 * ROWC + kt * 32);
#pragma unroll
        for (int n = 0; n < 4; ++n) {
          bf16x8 b = *reinterpret_cast<const bf16x8*>(pa + ((size_t)n * 8 + kt) * 512);
          acc[0][n] = __builtin_amdgcn_mfma_f32_16x16x32_bf16(a0, b, acc[0][n], 0, 0, 0);
          acc[1][n] = __builtin_amdgcn_mfma_f32_16x16x32_bf16(a1, b, acc[1][n], 0, 0, 0);
        }
      }
      unsigned short* yb = Y + node0 * 512 + wave * 64 + l15;
#pragma unroll
      for (int m = 0; m < 2; ++m)
#pragma unroll
        for (int r = 0; r < 4; ++r) {
          unsigned short* p = yb + (long long)(m * 16 + l4 * 4 + r) * 512;
#pragma unroll
          for (int n = 0; n < 4; ++n) p[n * 16] = f2bf(acc[m][n][r]);
        }
    }
    t = tn;
  }
}

// ---------------- Kernel B: out4 = 0.25*(Y[n]+Y[i0]+Y[i1]+Y[i2]) + b_agg ----------------
__device__ __forceinline__ float bf_lo(unsigned u) {
  union { unsigned x; float f; } c; c.x = u << 16; return c.f;
}
__device__ __forceinline__ float bf_hi(unsigned u) {
  union { unsigned x; float f; } c; c.x = u & 0xFFFF0000u; return c.f;
}

__global__ __launch_bounds__(256) void gather_kernel(
    const unsigned short* __restrict__ Y, const int* __restrict__ nbr,
    const float* __restrict__ b_agg, float* __restrict__ out4) {
  const int lane = threadIdx.x & 63;
  const int wid = (blockIdx.x * 256 + threadIdx.x) >> 6;
  const int nwaves = (GRID_B * 256) >> 6;

  float ba[8];
  const float* bp = b_agg + lane * 8;
#pragma unroll
  for (int j = 0; j < 8; ++j) ba[j] = bp[j];

  for (int n = wid; n < N_NODES; n += nwaves) {
    int i0 = nbr[3 * n + 0];
    int i1 = nbr[3 * n + 1];
    int i2 = nbr[3 * n + 2];
    i0 = i0 < 0 ? 0 : (i0 >= N_NODES ? N_NODES - 1 : i0);
    i1 = i1 < 0 ? 0 : (i1 >= N_NODES ? N_NODES - 1 : i1);
    i2 = i2 < 0 ? 0 : (i2 >= N_NODES ? N_NODES - 1 : i2);

    const uint4 a  = *reinterpret_cast<const uint4*>(Y + (size_t)n  * 512 + lane * 8);
    const uint4 b0 = *reinterpret_cast<const uint4*>(Y + (size_t)i0 * 512 + lane * 8);
    const uint4 b1 = *reinterpret_cast<const uint4*>(Y + (size_t)i1 * 512 + lane * 8);
    const uint4 b2 = *reinterpret_cast<const uint4*>(Y + (size_t)i2 * 512 + lane * 8);

    const unsigned wa[4] = {a.x, a.y, a.z, a.w};
    const unsigned w0[4] = {b0.x, b0.y, b0.z, b0.w};
    const unsigned w1[4] = {b1.x, b1.y, b1.z, b1.w};
    const unsigned w2[4] = {b2.x, b2.y, b2.z, b2.w};
    float s[8];
#pragma unroll
    for (int w = 0; w < 4; ++w) {
      s[2 * w]     = bf_lo(wa[w]) + bf_lo(w0[w]) + bf_lo(w1[w]) + bf_lo(w2[w]);
      s[2 * w + 1] = bf_hi(wa[w]) + bf_hi(w0[w]) + bf_hi(w1[w]) + bf_hi(w2[w]);
    }
    f32x4 o0 = {s[0] * 0.25f + ba[0], s[1] * 0.25f + ba[1],
                s[2] * 0.25f + ba[2], s[3] * 0.25f + ba[3]};
    f32x4 o1 = {s[4] * 0.25f + ba[4], s[5] * 0.25f + ba[5],
                s[6] * 0.25f + ba[6], s[7] * 0.25f + ba[7]};
    f32x4* op = reinterpret_cast<f32x4*>(out4 + (size_t)n * 512 + lane * 8);
    __builtin_nontemporal_store(o0, op);
    __builtin_nontemporal_store(o1, op + 1);
  }
}

// ---------------- Fallback (R2, known-good 600us) if ws too small for Y ----------------
__global__ __launch_bounds__(512, 4) void mesh_fused_fallback(
    const float* __restrict__ out1, const float* __restrict__ out2,
    const int* __restrict__ nbr,
    const unsigned short* __restrict__ Pc, const unsigned short* __restrict__ Pa,
    const float* __restrict__ b_comb, const float* __restrict__ b_agg,
    float* __restrict__ outp) {
  __shared__ unsigned short Acomb[BM * ROWC];
  __shared__ unsigned short Aagg[BM * ROWA];
  const int tid = threadIdx.x;
  const long long node0 = (long long)blockIdx.x * BM;
  {
    const int ln = tid >> 4, c16 = tid & 15;
    const long long gn = node0 + ln;
    long long i0 = nbr[3 * gn + 0], i1 = nbr[3 * gn + 1], i2 = nbr[3 * gn + 2];
    i0 = i0 < 0 ? 0 : (i0 >= N_NODES ? N_NODES - 1 : i0);
    i1 = i1 < 0 ? 0 : (i1 >= N_NODES ? N_NODES - 1 : i1);
    i2 = i2 < 0 ? 0 : (i2 >= N_NODES ? N_NODES - 1 : i2);
    const float4* r1 = reinterpret_cast<const float4*>(out1 + gn * 256);
    const float4* r2 = reinterpret_cast<const float4*>(out2 + gn * 256);
    const float4* g0 = reinterpret_cast<const float4*>(out2 + i0 * 256);
    const float4* g1 = reinterpret_cast<const float4*>(out2 + i1 * 256);
    const float4* g2 = reinterpret_cast<const float4*>(out2 + i2 * 256);
#pragma unroll
    for (int r = 0; r < 4; ++r) {
      const int c = c16 + 16 * r;
      float4 f1 = r1[c], f2 = r2[c], n0 = g0[c], n1 = g1[c], n2 = g2[c];
      float4 ag;
      ag.x = (f2.x + n0.x + n1.x + n2.x) * 0.25f;
      ag.y = (f2.y + n0.y + n1.y + n2.y) * 0.25f;
      ag.z = (f2.z + n0.z + n1.z + n2.z) * 0.25f;
      ag.w = (f2.w + n0.w + n1.w + n2.w) * 0.25f;
      st_bf4(&Acomb[(tid >> 4) * ROWC + c * 4], f1);
      st_bf4(&Acomb[(tid >> 4) * ROWC + 256 + c * 4], f2);
      st_bf4(&Aagg[(tid >> 4) * ROWA + c * 4], ag);
    }
  }
  __syncthreads();
  const int wave = tid >> 6, lane = tid & 63;
  const int l15 = lane & 15, l4 = lane >> 4;
  const int nt0 = wave * 4;
  float* o3 = outp;
  float* o4 = outp + (size_t)N_NODES * 512;
  {
    f32x4 acc[2][4];
#pragma unroll
    for (int m = 0; m < 2; ++m)
#pragma unroll
      for (int n = 0; n < 4; ++n) acc[m][n] = (f32x4){0.f, 0.f, 0.f, 0.f};
    const unsigned short* pc = Pc + (size_t)nt0 * 16 * 512 + lane * 8;
    const unsigned short* ab = &Acomb[(size_t)l15 * ROWC + l4 * 8];
#pragma unroll
    for (int kt = 0; kt < 16; ++kt) {
      bf16x8 a0 = *reinterpret_cast<const bf16x8*>(ab + kt * 32);
      bf16x8 a1 = *reinterpret_cast<const bf16x8*>(ab + 16 * ROWC + kt * 32);
#pragma unroll
      for (int n = 0; n < 4; ++n) {
        bf16x8 b = *reinterpret_cast<const bf16x8*>(pc + ((size_t)n * 16 + kt) * 512);
        acc[0][n] = __builtin_amdgcn_mfma_f32_16x16x32_bf16(a0, b, acc[0][n], 0, 0, 0);
        acc[1][n] = __builtin_amdgcn_mfma_f32_16x16x32_bf16(a1, b, acc[1][n], 0, 0, 0);
      }
    }
#pragma unroll
    for (int m = 0; m < 2; ++m)
#pragma unroll
      for (int r = 0; r < 4; ++r)
#pragma unroll
        for (int n = 0; n < 4; ++n) {
          const int col = wave * 64 + n * 16 + l15;
          o3[(node0 + m * 16 + l4 * 4 + r) * 512 + col] = acc[m][n][r] + b_comb[col];
        }
  }
  {
    f32x4 acc[2][4];
#pragma unroll
    for (int m = 0; m < 2; ++m)
#pragma unroll
      for (int n = 0; n < 4; ++n) acc[m][n] = (f32x4){0.f, 0.f, 0.f, 0.f};
    const unsigned short* pa = Pa + (size_t)nt0 * 8 * 512 + lane * 8;
    const unsigned short* ab = &Aagg[(size_t)l15 * ROWA + l4 * 8];
#pragma unroll
    for (int kt = 0; kt < 8; ++kt) {
      bf16x8 a0 = *reinterpret_cast<const bf16x8*>(ab + kt * 32);
      bf16x8 a1 = *reinterpret_cast<const bf16x8*>(ab + 16 * ROWA + kt * 32);
#pragma unroll
      for (int n = 0; n < 4; ++n) {
        bf16x8 b = *reinterpret_cast<const bf16x8*>(pa + ((size_t)n * 8 + kt) * 512);
        acc[0][n] = __builtin_amdgcn_mfma_f32_16x16x32_bf16(a0, b, acc[0][n], 0, 0, 0);
        acc[1][n] = __builtin_amdgcn_mfma_f32_16x16x32_bf16(a1, b, acc[1][n], 0, 0, 0);
      }
    }
#pragma unroll
    for (int m = 0; m < 2; ++m)
#pragma unroll
      for (int r = 0; r < 4; ++r)
#pragma unroll
        for (int n = 0; n < 4; ++n) {
          const int col = wave * 64 + n * 16 + l15;
          o4[(node0 + m * 16 + l4 * 4 + r) * 512 + col] = acc[m][n][r] + b_agg[col];
        }
  }
}

extern "C" void kernel_launch(void* const* d_in, const int* in_sizes, int n_in,
                              void* d_out, int out_size, void* d_ws, size_t ws_size,
                              hipStream_t stream) {
  const float* out1 = (const float*)d_in[0];
  const float* out2 = (const float*)d_in[1];
  const int* nbr = (const int*)d_in[2];  // harness pushes integers as int32
  const float* Wc = (const float*)d_in[3];
  const float* bc = (const float*)d_in[4];
  const float* Wa = (const float*)d_in[5];
  const float* ba = (const float*)d_in[6];

  const size_t yElems = (size_t)N_NODES * 512;           // bf16 Y: 204.8 MB
  const size_t packElems = 512 * 512 + 512 * 256;        // 768 KB
  const size_t need = (yElems + packElems) * 2;

  if (ws_size >= need) {
    unsigned short* Yw = (unsigned short*)d_ws;
    unsigned short* Pc = Yw + yElems;
    unsigned short* Pa = Pc + 512 * 512;
    pack_w_kernel<<<192, 256, 0, stream>>>(Wc, Wa, Pc, Pa);
    gemm_kernel<<<GRID_A, 512, 0, stream>>>(out1, out2, Pc, Pa, bc, (float*)d_out, Yw);
    gather_kernel<<<GRID_B, 256, 0, stream>>>(Yw, nbr, ba,
                                              (float*)d_out + (size_t)N_NODES * 512);
  } else {
    unsigned short* Pc = (unsigned short*)d_ws;
    unsigned short* Pa = Pc + 512 * 512;
    pack_w_kernel<<<192, 256, 0, stream>>>(Wc, Wa, Pc, Pa);
    mesh_fused_fallback<<<NTILES, 512, 0, stream>>>(out1, out2, nbr, Pc, Pa, bc, ba,
                                                    (float*)d_out);
  }
}

// Round 7
// 521.823 us; speedup vs baseline: 2.2125x; 2.2125x over previous
//
#include <hip/hip_runtime.h>

// Mesh2: out3 = [out1||out2] @ W_comb^T + b_comb ; out4 = mean(self+3nbrs) @ W_agg^T + b_agg
// R5/R6: LINEARITY SPLIT: Y = out2@W_agg^T (bf16 in ws), out4 = 0.25*(Y[n]+sum Y[nbr]) + b.
//        gather_kernel proven ~125us. gemm_kernel was 1020us: persistent prefetch defeated by
//        VGPR=64 cap, nt scalar stores + 32B-segment Y stores -> FETCH 1.2GB (RMW/spill).
// R7: kernel A rebuilt as R2's simple stage->sync->MFMA structure (no persistence, no nt):
//     - out3: plain cached scalar stores (proven clean in R2)
//     - Y: fragments -> LDS (reuse Acomb after reads complete) -> uint4 coalesced stores
//     - LDS 33KB only -> 4 blocks/CU for latency hiding. launch_bounds(512,4) (R2's no-spill cfg).

typedef __bf16 bf16x8 __attribute__((ext_vector_type(8)));
typedef float f32x4 __attribute__((ext_vector_type(4)));

#define N_NODES 200000
#define BM 32
#define NTILES (N_NODES / BM)  // 6250
#define ROWC 520               // 512 + 8 pad (bf16)
#define ROWA 264               // fallback only
#define GRID_B 2048

__device__ __forceinline__ unsigned short f2bf(float x) {
  union { float f; unsigned int u; } v; v.f = x;
  return (unsigned short)((v.u + 0x7FFFu + ((v.u >> 16) & 1u)) >> 16);  // RNE
}

__device__ __forceinline__ void st_bf4(unsigned short* p, float4 f) {
  uint2 w;
  w.x = (unsigned int)f2bf(f.x) | ((unsigned int)f2bf(f.y) << 16);
  w.y = (unsigned int)f2bf(f.z) | ((unsigned int)f2bf(f.w) << 16);
  *reinterpret_cast<uint2*>(p) = w;
}

// Pack W (f32, row-major [O][K]) -> bf16 MFMA-B-fragment-linear layout:
// tile (nt,kt): lane l holds W[nt*16 + (l&15)][kt*32 + (l>>4)*8 + j] at P[tile*512 + l*8 + j].
__global__ void pack_w_kernel(const float* __restrict__ Wc,
                              const float* __restrict__ Wa,
                              unsigned short* __restrict__ Pc,
                              unsigned short* __restrict__ Pa) {
  int t = blockIdx.x * 256 + threadIdx.x;
  if (t >= (512 + 256) * 64) return;
  int lane = t & 63;
  int tile = t >> 6;
  const float* W;
  unsigned short* P;
  int K, kt_n;
  if (tile < 512) { W = Wc; P = Pc; K = 512; kt_n = 16; }
  else { tile -= 512; W = Wa; P = Pa; K = 256; kt_n = 8; }
  int nt = tile / kt_n;
  int kt = tile - nt * kt_n;
  int row = nt * 16 + (lane & 15);
  int k0 = kt * 32 + (lane >> 4) * 8;
  const float* src = W + (size_t)row * K + k0;
  unsigned short* dst = P + (size_t)tile * 512 + lane * 8;
#pragma unroll
  for (int j = 0; j < 8; ++j) dst[j] = f2bf(src[j]);
}

// ---------------- Kernel A: dense GEMM (out3 f32 + Y bf16), simple R2 structure ----------------
__global__ __launch_bounds__(512, 4) void gemm_kernel(
    const float* __restrict__ out1, const float* __restrict__ out2,
    const unsigned short* __restrict__ Pc, const unsigned short* __restrict__ Pa,
    const float* __restrict__ b_comb,
    float* __restrict__ out3, unsigned short* __restrict__ Y) {
  __shared__ unsigned short Acomb[BM * ROWC];  // 33.3 KB -> 4 blocks/CU

  const int tid = threadIdx.x;
  const int ln = tid >> 4, c16 = tid & 15;  // stage role: node, chunk
  const int wave = tid >> 6, lane = tid & 63;
  const int l15 = lane & 15, l4 = lane >> 4;
  const long long node0 = (long long)blockIdx.x * BM;

  // ---- stage: 16 threads/node, out1|out2 -> bf16 LDS ----
  {
    const size_t gn = (size_t)node0 + ln;
    const float4* r1 = reinterpret_cast<const float4*>(out1 + gn * 256);
    const float4* r2 = reinterpret_cast<const float4*>(out2 + gn * 256);
#pragma unroll
    for (int r = 0; r < 4; ++r) {
      const int cc = c16 + 16 * r;
      st_bf4(&Acomb[ln * ROWC + cc * 4], r1[cc]);        // cols 0..255   = out1
      st_bf4(&Acomb[ln * ROWC + 256 + cc * 4], r2[cc]);  // cols 256..511 = out2
    }
  }
  __syncthreads();

  const int nt0 = wave * 4;

  // ---- out3 = [o1|o2] @ Wc^T + b (K=512) ----
  {
    f32x4 acc[2][4];
#pragma unroll
    for (int m = 0; m < 2; ++m)
#pragma unroll
      for (int n = 0; n < 4; ++n) acc[m][n] = (f32x4){0.f, 0.f, 0.f, 0.f};

    const unsigned short* pc = Pc + (size_t)nt0 * 16 * 512 + lane * 8;
    const unsigned short* ab = &Acomb[(size_t)l15 * ROWC + l4 * 8];
#pragma unroll
    for (int kt = 0; kt < 16; ++kt) {
      bf16x8 a0 = *reinterpret_cast<const bf16x8*>(ab + kt * 32);
      bf16x8 a1 = *reinterpret_cast<const bf16x8*>(ab + 16 * ROWC + kt * 32);
      bf16x8 bfr[4];
#pragma unroll
      for (int n = 0; n < 4; ++n)
        bfr[n] = *reinterpret_cast<const bf16x8*>(pc + ((size_t)n * 16 + kt) * 512);
#pragma unroll
      for (int n = 0; n < 4; ++n) {
        acc[0][n] = __builtin_amdgcn_mfma_f32_16x16x32_bf16(a0, bfr[n], acc[0][n], 0, 0, 0);
        acc[1][n] = __builtin_amdgcn_mfma_f32_16x16x32_bf16(a1, bfr[n], acc[1][n], 0, 0, 0);
      }
    }
    float* o3 = out3 + node0 * 512 + wave * 64 + l15;
#pragma unroll
    for (int m = 0; m < 2; ++m)
#pragma unroll
      for (int r = 0; r < 4; ++r) {
        float* p = o3 + (long long)(m * 16 + l4 * 4 + r) * 512;
#pragma unroll
        for (int n = 0; n < 4; ++n)
          p[n * 16] = acc[m][n][r] + b_comb[wave * 64 + n * 16 + l15];
      }
  }

  // ---- Y = o2 @ Wa^T (K=256, A = Acomb cols 256..511), frags -> LDS -> coalesced ----
  {
    f32x4 acc[2][4];
#pragma unroll
    for (int m = 0; m < 2; ++m)
#pragma unroll
      for (int n = 0; n < 4; ++n) acc[m][n] = (f32x4){0.f, 0.f, 0.f, 0.f};

    const unsigned short* pa = Pa + (size_t)nt0 * 8 * 512 + lane * 8;
    const unsigned short* ab = &Acomb[(size_t)l15 * ROWC + 256 + l4 * 8];
#pragma unroll
    for (int kt = 0; kt < 8; ++kt) {
      bf16x8 a0 = *reinterpret_cast<const bf16x8*>(ab + kt * 32);
      bf16x8 a1 = *reinterpret_cast<const bf16x8*>(ab + 16 * ROWC + kt * 32);
      bf16x8 bfr[4];
#pragma unroll
      for (int n = 0; n < 4; ++n)
        bfr[n] = *reinterpret_cast<const bf16x8*>(pa + ((size_t)n * 8 + kt) * 512);
#pragma unroll
      for (int n = 0; n < 4; ++n) {
        acc[0][n] = __builtin_amdgcn_mfma_f32_16x16x32_bf16(a0, bfr[n], acc[0][n], 0, 0, 0);
        acc[1][n] = __builtin_amdgcn_mfma_f32_16x16x32_bf16(a1, bfr[n], acc[1][n], 0, 0, 0);
      }
    }

    __syncthreads();  // all waves' LDS reads done -> safe to overwrite Acomb
#pragma unroll
    for (int m = 0; m < 2; ++m)
#pragma unroll
      for (int r = 0; r < 4; ++r) {
        const int row = m * 16 + l4 * 4 + r;
#pragma unroll
        for (int n = 0; n < 4; ++n)
          Acomb[row * ROWC + wave * 64 + n * 16 + l15] = f2bf(acc[m][n][r]);
      }
    __syncthreads();  // Y tile assembled in LDS

    // coalesced copy-out: 256B contiguous per quarter-wave, cached (gather reuses via L2/L3)
    {
      const int row = tid >> 4;
      const unsigned short* src = &Acomb[row * ROWC];
      unsigned short* dst = Y + (node0 + row) * 512;
#pragma unroll
      for (int j = 0; j < 4; ++j) {
        const int off = (c16 + 16 * j) * 8;
        *reinterpret_cast<uint4*>(dst + off) =
            *reinterpret_cast<const uint4*>(src + off);
      }
    }
  }
}

// ---------------- Kernel B: out4 = 0.25*(Y[n]+Y[i0]+Y[i1]+Y[i2]) + b_agg ----------------
__device__ __forceinline__ float bf_lo(unsigned u) {
  union { unsigned x; float f; } c; c.x = u << 16; return c.f;
}
__device__ __forceinline__ float bf_hi(unsigned u) {
  union { unsigned x; float f; } c; c.x = u & 0xFFFF0000u; return c.f;
}

__global__ __launch_bounds__(256) void gather_kernel(
    const unsigned short* __restrict__ Y, const int* __restrict__ nbr,
    const float* __restrict__ b_agg, float* __restrict__ out4) {
  const int lane = threadIdx.x & 63;
  const int wid = (blockIdx.x * 256 + threadIdx.x) >> 6;
  const int nwaves = (GRID_B * 256) >> 6;

  float ba[8];
  const float* bp = b_agg + lane * 8;
#pragma unroll
  for (int j = 0; j < 8; ++j) ba[j] = bp[j];

  for (int n = wid; n < N_NODES; n += nwaves) {
    int i0 = nbr[3 * n + 0];
    int i1 = nbr[3 * n + 1];
    int i2 = nbr[3 * n + 2];
    i0 = i0 < 0 ? 0 : (i0 >= N_NODES ? N_NODES - 1 : i0);
    i1 = i1 < 0 ? 0 : (i1 >= N_NODES ? N_NODES - 1 : i1);
    i2 = i2 < 0 ? 0 : (i2 >= N_NODES ? N_NODES - 1 : i2);

    const uint4 a  = *reinterpret_cast<const uint4*>(Y + (size_t)n  * 512 + lane * 8);
    const uint4 b0 = *reinterpret_cast<const uint4*>(Y + (size_t)i0 * 512 + lane * 8);
    const uint4 b1 = *reinterpret_cast<const uint4*>(Y + (size_t)i1 * 512 + lane * 8);
    const uint4 b2 = *reinterpret_cast<const uint4*>(Y + (size_t)i2 * 512 + lane * 8);

    const unsigned wa[4] = {a.x, a.y, a.z, a.w};
    const unsigned w0[4] = {b0.x, b0.y, b0.z, b0.w};
    const unsigned w1[4] = {b1.x, b1.y, b1.z, b1.w};
    const unsigned w2[4] = {b2.x, b2.y, b2.z, b2.w};
    float s[8];
#pragma unroll
    for (int w = 0; w < 4; ++w) {
      s[2 * w]     = bf_lo(wa[w]) + bf_lo(w0[w]) + bf_lo(w1[w]) + bf_lo(w2[w]);
      s[2 * w + 1] = bf_hi(wa[w]) + bf_hi(w0[w]) + bf_hi(w1[w]) + bf_hi(w2[w]);
    }
    f32x4 o0 = {s[0] * 0.25f + ba[0], s[1] * 0.25f + ba[1],
                s[2] * 0.25f + ba[2], s[3] * 0.25f + ba[3]};
    f32x4 o1 = {s[4] * 0.25f + ba[4], s[5] * 0.25f + ba[5],
                s[6] * 0.25f + ba[6], s[7] * 0.25f + ba[7]};
    f32x4* op = reinterpret_cast<f32x4*>(out4 + (size_t)n * 512 + lane * 8);
    __builtin_nontemporal_store(o0, op);
    __builtin_nontemporal_store(o1, op + 1);
  }
}

// ---------------- Fallback (R2, known-good) if ws too small for Y ----------------
__global__ __launch_bounds__(512, 4) void mesh_fused_fallback(
    const float* __restrict__ out1, const float* __restrict__ out2,
    const int* __restrict__ nbr,
    const unsigned short* __restrict__ Pc, const unsigned short* __restrict__ Pa,
    const float* __restrict__ b_comb, const float* __restrict__ b_agg,
    float* __restrict__ outp) {
  __shared__ unsigned short Acomb[BM * ROWC];
  __shared__ unsigned short Aagg[BM * ROWA];
  const int tid = threadIdx.x;
  const long long node0 = (long long)blockIdx.x * BM;
  {
    const int ln = tid >> 4, c16 = tid & 15;
    const long long gn = node0 + ln;
    long long i0 = nbr[3 * gn + 0], i1 = nbr[3 * gn + 1], i2 = nbr[3 * gn + 2];
    i0 = i0 < 0 ? 0 : (i0 >= N_NODES ? N_NODES - 1 : i0);
    i1 = i1 < 0 ? 0 : (i1 >= N_NODES ? N_NODES - 1 : i1);
    i2 = i2 < 0 ? 0 : (i2 >= N_NODES ? N_NODES - 1 : i2);
    const float4* r1 = reinterpret_cast<const float4*>(out1 + gn * 256);
    const float4* r2 = reinterpret_cast<const float4*>(out2 + gn * 256);
    const float4* g0 = reinterpret_cast<const float4*>(out2 + i0 * 256);
    const float4* g1 = reinterpret_cast<const float4*>(out2 + i1 * 256);
    const float4* g2 = reinterpret_cast<const float4*>(out2 + i2 * 256);
#pragma unroll
    for (int r = 0; r < 4; ++r) {
      const int c = c16 + 16 * r;
      float4 f1 = r1[c], f2 = r2[c], n0 = g0[c], n1 = g1[c], n2 = g2[c];
      float4 ag;
      ag.x = (f2.x + n0.x + n1.x + n2.x) * 0.25f;
      ag.y = (f2.y + n0.y + n1.y + n2.y) * 0.25f;
      ag.z = (f2.z + n0.z + n1.z + n2.z) * 0.25f;
      ag.w = (f2.w + n0.w + n1.w + n2.w) * 0.25f;
      st_bf4(&Acomb[(tid >> 4) * ROWC + c * 4], f1);
      st_bf4(&Acomb[(tid >> 4) * ROWC + 256 + c * 4], f2);
      st_bf4(&Aagg[(tid >> 4) * ROWA + c * 4], ag);
    }
  }
  __syncthreads();
  const int wave = tid >> 6, lane = tid & 63;
  const int l15 = lane & 15, l4 = lane >> 4;
  const int nt0 = wave * 4;
  float* o3 = outp;
  float* o4 = outp + (size_t)N_NODES * 512;
  {
    f32x4 acc[2][4];
#pragma unroll
    for (int m = 0; m < 2; ++m)
#pragma unroll
      for (int n = 0; n < 4; ++n) acc[m][n] = (f32x4){0.f, 0.f, 0.f, 0.f};
    const unsigned short* pc = Pc + (size_t)nt0 * 16 * 512 + lane * 8;
    const unsigned short* ab = &Acomb[(size_t)l15 * ROWC + l4 * 8];
#pragma unroll
    for (int kt = 0; kt < 16; ++kt) {
      bf16x8 a0 = *reinterpret_cast<const bf16x8*>(ab + kt * 32);
      bf16x8 a1 = *reinterpret_cast<const bf16x8*>(ab + 16 * ROWC + kt * 32);
#pragma unroll
      for (int n = 0; n < 4; ++n) {
        bf16x8 b = *reinterpret_cast<const bf16x8*>(pc + ((size_t)n * 16 + kt) * 512);
        acc[0][n] = __builtin_amdgcn_mfma_f32_16x16x32_bf16(a0, b, acc[0][n], 0, 0, 0);
        acc[1][n] = __builtin_amdgcn_mfma_f32_16x16x32_bf16(a1, b, acc[1][n], 0, 0, 0);
      }
    }
#pragma unroll
    for (int m = 0; m < 2; ++m)
#pragma unroll
      for (int r = 0; r < 4; ++r)
#pragma unroll
        for (int n = 0; n < 4; ++n) {
          const int col = wave * 64 + n * 16 + l15;
          o3[(node0 + m * 16 + l4 * 4 + r) * 512 + col] = acc[m][n][r] + b_comb[col];
        }
  }
  {
    f32x4 acc[2][4];
#pragma unroll
    for (int m = 0; m < 2; ++m)
#pragma unroll
      for (int n = 0; n < 4; ++n) acc[m][n] = (f32x4){0.f, 0.f, 0.f, 0.f};
    const unsigned short* pa = Pa + (size_t)nt0 * 8 * 512 + lane * 8;
    const unsigned short* ab = &Aagg[(size_t)l15 * ROWA + l4 * 8];
#pragma unroll
    for (int kt = 0; kt < 8; ++kt) {
      bf16x8 a0 = *reinterpret_cast<const bf16x8*>(ab + kt * 32);
      bf16x8 a1 = *reinterpret_cast<const bf16x8*>(ab + 16 * ROWA + kt * 32);
#pragma unroll
      for (int n = 0; n < 4; ++n) {
        bf16x8 b = *reinterpret_cast<const bf16x8*>(pa + ((size_t)n * 8 + kt) * 512);
        acc[0][n] = __builtin_amdgcn_mfma_f32_16x16x32_bf16(a0, b, acc[0][n], 0, 0, 0);
        acc[1][n] = __builtin_amdgcn_mfma_f32_16x16x32_bf16(a1, b, acc[1][n], 0, 0, 0);
      }
    }
#pragma unroll
    for (int m = 0; m < 2; ++m)
#pragma unroll
      for (int r = 0; r < 4; ++r)
#pragma unroll
        for (int n = 0; n < 4; ++n) {
          const int col = wave * 64 + n * 16 + l15;
          o4[(node0 + m * 16 + l4 * 4 + r) * 512 + col] = acc[m][n][r] + b_agg[col];
        }
  }
}

extern "C" void kernel_launch(void* const* d_in, const int* in_sizes, int n_in,
                              void* d_out, int out_size, void* d_ws, size_t ws_size,
                              hipStream_t stream) {
  const float* out1 = (const float*)d_in[0];
  const float* out2 = (const float*)d_in[1];
  const int* nbr = (const int*)d_in[2];  // harness pushes integers as int32
  const float* Wc = (const float*)d_in[3];
  const float* bc = (const float*)d_in[4];
  const float* Wa = (const float*)d_in[5];
  const float* ba = (const float*)d_in[6];

  const size_t yElems = (size_t)N_NODES * 512;     // bf16 Y: 204.8 MB
  const size_t packElems = 512 * 512 + 512 * 256;  // 768 KB
  const size_t need = (yElems + packElems) * 2;

  if (ws_size >= need) {
    unsigned short* Yw = (unsigned short*)d_ws;
    unsigned short* Pc = Yw + yElems;
    unsigned short* Pa = Pc + 512 * 512;
    pack_w_kernel<<<192, 256, 0, stream>>>(Wc, Wa, Pc, Pa);
    gemm_kernel<<<NTILES, 512, 0, stream>>>(out1, out2, Pc, Pa, bc, (float*)d_out, Yw);
    gather_kernel<<<GRID_B, 256, 0, stream>>>(Yw, nbr, ba,
                                              (float*)d_out + (size_t)N_NODES * 512);
  } else {
    unsigned short* Pc = (unsigned short*)d_ws;
    unsigned short* Pa = Pc + 512 * 512;
    pack_w_kernel<<<192, 256, 0, stream>>>(Wc, Wa, Pc, Pa);
    mesh_fused_fallback<<<NTILES, 512, 0, stream>>>(out1, out2, nbr, Pc, Pa, bc, ba,
                                                    (float*)d_out);
  }
}

// Round 8
// 519.916 us; speedup vs baseline: 2.2206x; 1.0037x over previous
//
#include <hip/hip_runtime.h>

// Mesh2: out3 = [out1||out2] @ W_comb^T + b_comb ; out4 = mean(self+3nbrs) @ W_agg^T + b_agg
// R5-R7: LINEARITY SPLIT (Y = out2@W_agg^T in ws; gather in output space) -> 522us total:
//        gemm ~390us, gather ~125us. gemm is L2-issue-bound in compute phase: every block
//        re-reads all 768KB of packed B from L2; at BM=32 each B-frag feeds only 2 MFMAs.
// R8: BM=64 (M_rep=4/wave): B-frag reg reuse x4 -> per-MFMA L2 B-traffic halves (4.8->2.4GB),
//     barriers per node halve. LDS 66.6KB -> 2 blocks/CU. Same simple structure (no pipelining
//     -- three attempts all spilled; compiler's VGPR heuristic wins).

typedef __bf16 bf16x8 __attribute__((ext_vector_type(8)));
typedef float f32x4 __attribute__((ext_vector_type(4)));

#define N_NODES 200000
#define BM 64
#define NTILES (N_NODES / BM)  // 3125 exact
#define ROWC 520               // 512 + 8 pad (bf16) -> conflict-free quarter-wave b128
#define ROWA 264               // fallback only
#define GRID_B 2048

__device__ __forceinline__ unsigned short f2bf(float x) {
  union { float f; unsigned int u; } v; v.f = x;
  return (unsigned short)((v.u + 0x7FFFu + ((v.u >> 16) & 1u)) >> 16);  // RNE
}

__device__ __forceinline__ void st_bf4(unsigned short* p, float4 f) {
  uint2 w;
  w.x = (unsigned int)f2bf(f.x) | ((unsigned int)f2bf(f.y) << 16);
  w.y = (unsigned int)f2bf(f.z) | ((unsigned int)f2bf(f.w) << 16);
  *reinterpret_cast<uint2*>(p) = w;
}

// Pack W (f32, row-major [O][K]) -> bf16 MFMA-B-fragment-linear layout:
// tile (nt,kt): lane l holds W[nt*16 + (l&15)][kt*32 + (l>>4)*8 + j] at P[tile*512 + l*8 + j].
__global__ void pack_w_kernel(const float* __restrict__ Wc,
                              const float* __restrict__ Wa,
                              unsigned short* __restrict__ Pc,
                              unsigned short* __restrict__ Pa) {
  int t = blockIdx.x * 256 + threadIdx.x;
  if (t >= (512 + 256) * 64) return;
  int lane = t & 63;
  int tile = t >> 6;
  const float* W;
  unsigned short* P;
  int K, kt_n;
  if (tile < 512) { W = Wc; P = Pc; K = 512; kt_n = 16; }
  else { tile -= 512; W = Wa; P = Pa; K = 256; kt_n = 8; }
  int nt = tile / kt_n;
  int kt = tile - nt * kt_n;
  int row = nt * 16 + (lane & 15);
  int k0 = kt * 32 + (lane >> 4) * 8;
  const float* src = W + (size_t)row * K + k0;
  unsigned short* dst = P + (size_t)tile * 512 + lane * 8;
#pragma unroll
  for (int j = 0; j < 8; ++j) dst[j] = f2bf(src[j]);
}

// ---------------- Kernel A: dense GEMM (out3 f32 + Y bf16), BM=64 ----------------
__global__ __launch_bounds__(512, 4) void gemm_kernel(
    const float* __restrict__ out1, const float* __restrict__ out2,
    const unsigned short* __restrict__ Pc, const unsigned short* __restrict__ Pa,
    const float* __restrict__ b_comb,
    float* __restrict__ out3, unsigned short* __restrict__ Y) {
  __shared__ unsigned short Acomb[BM * ROWC];  // 66.56 KB -> 2 blocks/CU

  const int tid = threadIdx.x;
  const int ln8 = tid >> 3, c8 = tid & 7;  // stage role: node (0..63), chunk (0..7)
  const int wave = tid >> 6, lane = tid & 63;
  const int l15 = lane & 15, l4 = lane >> 4;
  const long long node0 = (long long)blockIdx.x * BM;

  float bcv[4];
#pragma unroll
  for (int n = 0; n < 4; ++n) bcv[n] = b_comb[wave * 64 + n * 16 + l15];

  // ---- stage: 8 threads/node, out1|out2 -> bf16 LDS ----
  {
    const size_t gn = (size_t)node0 + ln8;
    const float4* r1 = reinterpret_cast<const float4*>(out1 + gn * 256);
    const float4* r2 = reinterpret_cast<const float4*>(out2 + gn * 256);
#pragma unroll
    for (int r = 0; r < 8; ++r) {
      const int cc = c8 + 8 * r;  // float4 index 0..63
      st_bf4(&Acomb[ln8 * ROWC + cc * 4], r1[cc]);        // cols 0..255   = out1
      st_bf4(&Acomb[ln8 * ROWC + 256 + cc * 4], r2[cc]);  // cols 256..511 = out2
    }
  }
  __syncthreads();

  const int nt0 = wave * 4;

  // ---- out3 = [o1|o2] @ Wc^T + b (K=512), M_rep=4: B-frag reuse x4 ----
  {
    f32x4 acc[4][4];
#pragma unroll
    for (int m = 0; m < 4; ++m)
#pragma unroll
      for (int n = 0; n < 4; ++n) acc[m][n] = (f32x4){0.f, 0.f, 0.f, 0.f};

    const unsigned short* pc = Pc + (size_t)nt0 * 16 * 512 + lane * 8;
    const unsigned short* ab = &Acomb[(size_t)l15 * ROWC + l4 * 8];
#pragma unroll
    for (int kt = 0; kt < 16; ++kt) {
      bf16x8 bfr[4];
#pragma unroll
      for (int n = 0; n < 4; ++n)
        bfr[n] = *reinterpret_cast<const bf16x8*>(pc + ((size_t)n * 16 + kt) * 512);
      bf16x8 av[4];
#pragma unroll
      for (int m = 0; m < 4; ++m)
        av[m] = *reinterpret_cast<const bf16x8*>(ab + (size_t)m * 16 * ROWC + kt * 32);
#pragma unroll
      for (int m = 0; m < 4; ++m)
#pragma unroll
        for (int n = 0; n < 4; ++n)
          acc[m][n] = __builtin_amdgcn_mfma_f32_16x16x32_bf16(av[m], bfr[n], acc[m][n], 0, 0, 0);
    }
    float* o3 = out3 + node0 * 512 + wave * 64 + l15;
#pragma unroll
    for (int m = 0; m < 4; ++m)
#pragma unroll
      for (int r = 0; r < 4; ++r) {
        float* p = o3 + (long long)(m * 16 + l4 * 4 + r) * 512;
#pragma unroll
        for (int n = 0; n < 4; ++n) p[n * 16] = acc[m][n][r] + bcv[n];
      }
  }

  // ---- Y = o2 @ Wa^T (K=256, A = Acomb cols 256..511), frags -> LDS -> coalesced ----
  {
    f32x4 acc[4][4];
#pragma unroll
    for (int m = 0; m < 4; ++m)
#pragma unroll
      for (int n = 0; n < 4; ++n) acc[m][n] = (f32x4){0.f, 0.f, 0.f, 0.f};

    const unsigned short* pa = Pa + (size_t)nt0 * 8 * 512 + lane * 8;
    const unsigned short* ab = &Acomb[(size_t)l15 * ROWC + 256 + l4 * 8];
#pragma unroll
    for (int kt = 0; kt < 8; ++kt) {
      bf16x8 bfr[4];
#pragma unroll
      for (int n = 0; n < 4; ++n)
        bfr[n] = *reinterpret_cast<const bf16x8*>(pa + ((size_t)n * 8 + kt) * 512);
      bf16x8 av[4];
#pragma unroll
      for (int m = 0; m < 4; ++m)
        av[m] = *reinterpret_cast<const bf16x8*>(ab + (size_t)m * 16 * ROWC + kt * 32);
#pragma unroll
      for (int m = 0; m < 4; ++m)
#pragma unroll
        for (int n = 0; n < 4; ++n)
          acc[m][n] = __builtin_amdgcn_mfma_f32_16x16x32_bf16(av[m], bfr[n], acc[m][n], 0, 0, 0);
    }

    __syncthreads();  // all waves' LDS reads done -> safe to overwrite Acomb
#pragma unroll
    for (int m = 0; m < 4; ++m)
#pragma unroll
      for (int r = 0; r < 4; ++r) {
        const int row = m * 16 + l4 * 4 + r;
#pragma unroll
        for (int n = 0; n < 4; ++n)
          Acomb[row * ROWC + wave * 64 + n * 16 + l15] = f2bf(acc[m][n][r]);
      }
    __syncthreads();  // Y tile assembled in LDS

    // coalesced copy-out: 8 threads/row, 8x uint4 each, cached (gather reuses via L2/L3)
    {
      const unsigned short* src = &Acomb[ln8 * ROWC];
      unsigned short* dst = Y + (node0 + ln8) * 512;
#pragma unroll
      for (int j = 0; j < 8; ++j) {
        const int e = (c8 + 8 * j) * 8;  // bf16 element offset, 16B-aligned
        *reinterpret_cast<uint4*>(dst + e) = *reinterpret_cast<const uint4*>(src + e);
      }
    }
  }
}

// ---------------- Kernel B: out4 = 0.25*(Y[n]+Y[i0]+Y[i1]+Y[i2]) + b_agg ----------------
__device__ __forceinline__ float bf_lo(unsigned u) {
  union { unsigned x; float f; } c; c.x = u << 16; return c.f;
}
__device__ __forceinline__ float bf_hi(unsigned u) {
  union { unsigned x; float f; } c; c.x = u & 0xFFFF0000u; return c.f;
}

__global__ __launch_bounds__(256) void gather_kernel(
    const unsigned short* __restrict__ Y, const int* __restrict__ nbr,
    const float* __restrict__ b_agg, float* __restrict__ out4) {
  const int lane = threadIdx.x & 63;
  const int wid = (blockIdx.x * 256 + threadIdx.x) >> 6;
  const int nwaves = (GRID_B * 256) >> 6;

  float ba[8];
  const float* bp = b_agg + lane * 8;
#pragma unroll
  for (int j = 0; j < 8; ++j) ba[j] = bp[j];

  for (int n = wid; n < N_NODES; n += nwaves) {
    int i0 = nbr[3 * n + 0];
    int i1 = nbr[3 * n + 1];
    int i2 = nbr[3 * n + 2];
    i0 = i0 < 0 ? 0 : (i0 >= N_NODES ? N_NODES - 1 : i0);
    i1 = i1 < 0 ? 0 : (i1 >= N_NODES ? N_NODES - 1 : i1);
    i2 = i2 < 0 ? 0 : (i2 >= N_NODES ? N_NODES - 1 : i2);

    const uint4 a  = *reinterpret_cast<const uint4*>(Y + (size_t)n  * 512 + lane * 8);
    const uint4 b0 = *reinterpret_cast<const uint4*>(Y + (size_t)i0 * 512 + lane * 8);
    const uint4 b1 = *reinterpret_cast<const uint4*>(Y + (size_t)i1 * 512 + lane * 8);
    const uint4 b2 = *reinterpret_cast<const uint4*>(Y + (size_t)i2 * 512 + lane * 8);

    const unsigned wa[4] = {a.x, a.y, a.z, a.w};
    const unsigned w0[4] = {b0.x, b0.y, b0.z, b0.w};
    const unsigned w1[4] = {b1.x, b1.y, b1.z, b1.w};
    const unsigned w2[4] = {b2.x, b2.y, b2.z, b2.w};
    float s[8];
#pragma unroll
    for (int w = 0; w < 4; ++w) {
      s[2 * w]     = bf_lo(wa[w]) + bf_lo(w0[w]) + bf_lo(w1[w]) + bf_lo(w2[w]);
      s[2 * w + 1] = bf_hi(wa[w]) + bf_hi(w0[w]) + bf_hi(w1[w]) + bf_hi(w2[w]);
    }
    f32x4 o0 = {s[0] * 0.25f + ba[0], s[1] * 0.25f + ba[1],
                s[2] * 0.25f + ba[2], s[3] * 0.25f + ba[3]};
    f32x4 o1 = {s[4] * 0.25f + ba[4], s[5] * 0.25f + ba[5],
                s[6] * 0.25f + ba[6], s[7] * 0.25f + ba[7]};
    f32x4* op = reinterpret_cast<f32x4*>(out4 + (size_t)n * 512 + lane * 8);
    __builtin_nontemporal_store(o0, op);
    __builtin_nontemporal_store(o1, op + 1);
  }
}

// ---------------- Fallback (R2-style, known-good) if ws too small for Y ----------------
__global__ __launch_bounds__(512, 4) void mesh_fused_fallback(
    const float* __restrict__ out1, const float* __restrict__ out2,
    const int* __restrict__ nbr,
    const unsigned short* __restrict__ Pc, const unsigned short* __restrict__ Pa,
    const float* __restrict__ b_comb, const float* __restrict__ b_agg,
    float* __restrict__ outp) {
  __shared__ unsigned short Ac[32 * ROWC];
  __shared__ unsigned short Aagg[32 * ROWA];
  const int tid = threadIdx.x;
  const long long node0 = (long long)blockIdx.x * 32;
  {
    const int ln = tid >> 4, c16 = tid & 15;
    const long long gn = node0 + ln;
    long long i0 = nbr[3 * gn + 0], i1 = nbr[3 * gn + 1], i2 = nbr[3 * gn + 2];
    i0 = i0 < 0 ? 0 : (i0 >= N_NODES ? N_NODES - 1 : i0);
    i1 = i1 < 0 ? 0 : (i1 >= N_NODES ? N_NODES - 1 : i1);
    i2 = i2 < 0 ? 0 : (i2 >= N_NODES ? N_NODES - 1 : i2);
    const float4* r1 = reinterpret_cast<const float4*>(out1 + gn * 256);
    const float4* r2 = reinterpret_cast<const float4*>(out2 + gn * 256);
    const float4* g0 = reinterpret_cast<const float4*>(out2 + i0 * 256);
    const float4* g1 = reinterpret_cast<const float4*>(out2 + i1 * 256);
    const float4* g2 = reinterpret_cast<const float4*>(out2 + i2 * 256);
#pragma unroll
    for (int r = 0; r < 4; ++r) {
      const int c = c16 + 16 * r;
      float4 f1 = r1[c], f2 = r2[c], n0 = g0[c], n1 = g1[c], n2 = g2[c];
      float4 ag;
      ag.x = (f2.x + n0.x + n1.x + n2.x) * 0.25f;
      ag.y = (f2.y + n0.y + n1.y + n2.y) * 0.25f;
      ag.z = (f2.z + n0.z + n1.z + n2.z) * 0.25f;
      ag.w = (f2.w + n0.w + n1.w + n2.w) * 0.25f;
      st_bf4(&Ac[ln * ROWC + c * 4], f1);
      st_bf4(&Ac[ln * ROWC + 256 + c * 4], f2);
      st_bf4(&Aagg[ln * ROWA + c * 4], ag);
    }
  }
  __syncthreads();
  const int wave = tid >> 6, lane = tid & 63;
  const int l15 = lane & 15, l4 = lane >> 4;
  const int nt0 = wave * 4;
  float* o3 = outp;
  float* o4 = outp + (size_t)N_NODES * 512;
  {
    f32x4 acc[2][4];
#pragma unroll
    for (int m = 0; m < 2; ++m)
#pragma unroll
      for (int n = 0; n < 4; ++n) acc[m][n] = (f32x4){0.f, 0.f, 0.f, 0.f};
    const unsigned short* pc = Pc + (size_t)nt0 * 16 * 512 + lane * 8;
    const unsigned short* ab = &Ac[(size_t)l15 * ROWC + l4 * 8];
#pragma unroll
    for (int kt = 0; kt < 16; ++kt) {
      bf16x8 a0 = *reinterpret_cast<const bf16x8*>(ab + kt * 32);
      bf16x8 a1 = *reinterpret_cast<const bf16x8*>(ab + 16 * ROWC + kt * 32);
#pragma unroll
      for (int n = 0; n < 4; ++n) {
        bf16x8 b = *reinterpret_cast<const bf16x8*>(pc + ((size_t)n * 16 + kt) * 512);
        acc[0][n] = __builtin_amdgcn_mfma_f32_16x16x32_bf16(a0, b, acc[0][n], 0, 0, 0);
        acc[1][n] = __builtin_amdgcn_mfma_f32_16x16x32_bf16(a1, b, acc[1][n], 0, 0, 0);
      }
    }
#pragma unroll
    for (int m = 0; m < 2; ++m)
#pragma unroll
      for (int r = 0; r < 4; ++r)
#pragma unroll
        for (int n = 0; n < 4; ++n) {
          const int col = wave * 64 + n * 16 + l15;
          o3[(node0 + m * 16 + l4 * 4 + r) * 512 + col] = acc[m][n][r] + b_comb[col];
        }
  }
  {
    f32x4 acc[2][4];
#pragma unroll
    for (int m = 0; m < 2; ++m)
#pragma unroll
      for (int n = 0; n < 4; ++n) acc[m][n] = (f32x4){0.f, 0.f, 0.f, 0.f};
    const unsigned short* pa = Pa + (size_t)nt0 * 8 * 512 + lane * 8;
    const unsigned short* ab = &Aagg[(size_t)l15 * ROWA + l4 * 8];
#pragma unroll
    for (int kt = 0; kt < 8; ++kt) {
      bf16x8 a0 = *reinterpret_cast<const bf16x8*>(ab + kt * 32);
      bf16x8 a1 = *reinterpret_cast<const bf16x8*>(ab + 16 * ROWA + kt * 32);
#pragma unroll
      for (int n = 0; n < 4; ++n) {
        bf16x8 b = *reinterpret_cast<const bf16x8*>(pa + ((size_t)n * 8 + kt) * 512);
        acc[0][n] = __builtin_amdgcn_mfma_f32_16x16x32_bf16(a0, b, acc[0][n], 0, 0, 0);
        acc[1][n] = __builtin_amdgcn_mfma_f32_16x16x32_bf16(a1, b, acc[1][n], 0, 0, 0);
      }
    }
#pragma unroll
    for (int m = 0; m < 2; ++m)
#pragma unroll
      for (int r = 0; r < 4; ++r)
#pragma unroll
        for (int n = 0; n < 4; ++n) {
          const int col = wave * 64 + n * 16 + l15;
          o4[(node0 + m * 16 + l4 * 4 + r) * 512 + col] = acc[m][n][r] + b_agg[col];
        }
  }
}

extern "C" void kernel_launch(void* const* d_in, const int* in_sizes, int n_in,
                              void* d_out, int out_size, void* d_ws, size_t ws_size,
                              hipStream_t stream) {
  const float* out1 = (const float*)d_in[0];
  const float* out2 = (const float*)d_in[1];
  const int* nbr = (const int*)d_in[2];  // harness pushes integers as int32
  const float* Wc = (const float*)d_in[3];
  const float* bc = (const float*)d_in[4];
  const float* Wa = (const float*)d_in[5];
  const float* ba = (const float*)d_in[6];

  const size_t yElems = (size_t)N_NODES * 512;     // bf16 Y: 204.8 MB
  const size_t packElems = 512 * 512 + 512 * 256;  // 768 KB
  const size_t need = (yElems + packElems) * 2;

  if (ws_size >= need) {
    unsigned short* Yw = (unsigned short*)d_ws;
    unsigned short* Pc = Yw + yElems;
    unsigned short* Pa = Pc + 512 * 512;
    pack_w_kernel<<<192, 256, 0, stream>>>(Wc, Wa, Pc, Pa);
    gemm_kernel<<<NTILES, 512, 0, stream>>>(out1, out2, Pc, Pa, bc, (float*)d_out, Yw);
    gather_kernel<<<GRID_B, 256, 0, stream>>>(Yw, nbr, ba,
                                              (float*)d_out + (size_t)N_NODES * 512);
  } else {
    unsigned short* Pc = (unsigned short*)d_ws;
    unsigned short* Pa = Pc + 512 * 512;
    pack_w_kernel<<<192, 256, 0, stream>>>(Wc, Wa, Pc, Pa);
    mesh_fused_fallback<<<N_NODES / 32, 512, 0, stream>>>(out1, out2, nbr, Pc, Pa, bc, ba,
                                                          (float*)d_out);
  }
}